// Round 1
// baseline (117.949 us; speedup 1.0000x reference)
//
#include <hip/hip_runtime.h>
#include <hip/hip_bf16.h>

// RoIPool max over boolean cell masks (harness bf16-ifies floats AND bools).
// B=8, C=256, H=W=64 (HW=4096), N=128 cells (16/image).
// R6 structure (attack stall-bound R5 main kernel: ~40us despite ~6us of VALU work):
//   kernel 1: pack 16 cell masks/image -> uint16 per pixel (64 KB in d_ws).
//             512 blocks x 64 thr; cnt==16 fast path fully unrolled so all 16
//             mask loads are in flight at once (R5's runtime-trip loop serialized
//             16 x ~900cy HBM latencies with 0.5 waves/SIMD of TLP).
//   kernel 2: ONE WAVE per (b,c): barrier-free, LDS-free. Lane owns 64 px
//             (8 x uint4 bf16 loads issued upfront), bit-domain select
//             (bfe+bfi+max3), 64-lane shfl_xor butterfly for all 16 cells,
//             scatter store from lanes 0..15 via compile-time cndmask chain.

#define HW    4096
#define BIMG  8
#define CCH   256
#define NCELL 128

__device__ __forceinline__ void cell_range(const int* counts, int b, int& start, int& cnt) {
    start = 0;
    for (int i = 0; i < b; ++i) start += counts[i];
    if (start > NCELL) start = NCELL;
    cnt = counts[b];
    // jnp.repeat(..., total_repeat_length=N) pads with the last value:
    if (b == BIMG - 1 && start + cnt < NCELL) cnt = NCELL - start;
    if (cnt > 16) cnt = 16;
    if (start + cnt > NCELL) cnt = NCELL - start;
    if (cnt < 0) cnt = 0;
}

// ---- kernel 1: bit-pack masks. grid 512 x 64 threads = 32768 = BIMG*HW ----
__global__ __launch_bounds__(64)
void pack_masks(const void* __restrict__ maskv,
                const int* __restrict__ counts,
                unsigned short* __restrict__ packed) {
    const int tid = threadIdx.x;                 // 0..63 (one wave per block)
    const int idx = blockIdx.x * 64 + tid;       // b*HW + p
    const int b = idx >> 12;
    const int p = idx & (HW - 1);

    // mask element size from byte-lane OR of first 1 KiB (proven R3/R4/R5),
    // now wave-level: butterfly OR, no LDS, no barrier.
    const unsigned* mw0 = (const unsigned*)maskv;
    unsigned ow = mw0[tid * 4] | mw0[tid * 4 + 1] | mw0[tid * 4 + 2] | mw0[tid * 4 + 3];
    #pragma unroll
    for (int d = 1; d < 64; d <<= 1) ow |= __shfl_xor(ow, d, 64);
    const unsigned or0 = ow & 0xFFu, or1 = (ow >> 8) & 0xFFu;
    int msize;
    if (or1 == 0)                        msize = 4;  // int32/f32 masks
    else if (or0 == 0x80 || or0 == 0x00) msize = 2;  // bf16 (3F80) / f16 (3C00)
    else                                 msize = 1;  // bool/uint8

    int start, cnt;
    cell_range(counts, b, start, cnt);

    unsigned w = 0;
    if (msize == 2) {
        const unsigned short* mh = (const unsigned short*)maskv + (size_t)start * HW + p;
        if (cnt == 16) {
            #pragma unroll
            for (int j = 0; j < 16; ++j)
                w |= (mh[(size_t)j * HW] ? 1u : 0u) << j;   // 16 loads in flight
        } else {
            for (int j = 0; j < cnt; ++j)
                w |= (mh[(size_t)j * HW] ? 1u : 0u) << j;
        }
    } else if (msize == 4) {
        const unsigned* mw = (const unsigned*)maskv + (size_t)start * HW + p;
        if (cnt == 16) {
            #pragma unroll
            for (int j = 0; j < 16; ++j)
                w |= (mw[(size_t)j * HW] ? 1u : 0u) << j;
        } else {
            for (int j = 0; j < cnt; ++j)
                w |= (mw[(size_t)j * HW] ? 1u : 0u) << j;
        }
    } else {
        const unsigned char* mb = (const unsigned char*)maskv + (size_t)start * HW + p;
        if (cnt == 16) {
            #pragma unroll
            for (int j = 0; j < 16; ++j)
                w |= (mb[(size_t)j * HW] ? 1u : 0u) << j;
        } else {
            for (int j = 0; j < cnt; ++j)
                w |= (mb[(size_t)j * HW] ? 1u : 0u) << j;
        }
    }
    packed[idx] = (unsigned short)w;
}

// ---- kernel 2: one WAVE per (b, c). grid 512 x 256 thr (4 waves/block) ----
__global__ __launch_bounds__(256, 2)
void roipool_main(const void* __restrict__ featv,
                  const unsigned short* __restrict__ packed,
                  const int* __restrict__ counts,
                  void* __restrict__ outv) {
    const int tid = threadIdx.x;
    const int l   = tid & 63;                     // lane
    const int bc  = blockIdx.x * 4 + (tid >> 6);  // wave -> (b,c), 2048 waves
    const int c   = bc & (CCH - 1);
    const int b   = bc >> 8;
    const float NEG = -__builtin_inff();
    const unsigned NEGI = 0xFF800000u;            // f32 -inf bits

    // feature dtype: bf16 iff byte1 of each dword looks like a bf16 exponent
    // byte (proven R5 heuristic) — wave-level ballot, no LDS, no barrier.
    const unsigned* fw_ = (const unsigned*)featv;
    const unsigned w0 = fw_[l];
    const unsigned eb = (w0 >> 8) & 0x7F;
    const unsigned long long bm = __ballot(eb >= 0x3B && eb <= 0x41);
    const int fbf16 = (__popcll(bm) >= 48);

    int start, cnt;
    cell_range(counts, b, start, cnt);

    // packed masks: chunk i covers pixels (i*64 + l)*8 .. +7; dword k of the
    // uint4 holds the uint16 masks of pixel pair (2k, 2k+1) within the chunk.
    const unsigned short* pk = packed + ((size_t)b << 12);
    uint4 pm[8];
    #pragma unroll
    for (int i = 0; i < 8; ++i)
        pm[i] = *(const uint4*)(pk + (i * 64 + l) * 8);   // 8 x 16B, coalesced

    float vmax[16];
    #pragma unroll
    for (int j = 0; j < 16; ++j) vmax[j] = NEG;

    if (fbf16) {
        const unsigned short* fp = (const unsigned short*)featv
                                 + (((size_t)(b * CCH + c)) << 12);
        #pragma unroll
        for (int i = 0; i < 8; ++i) {
            uint4 f = *(const uint4*)(fp + (i * 64 + l) * 8);  // 8 bf16 px
            const unsigned fw4[4] = {f.x, f.y, f.z, f.w};
            const unsigned mw4[4] = {pm[i].x, pm[i].y, pm[i].z, pm[i].w};
            #pragma unroll
            for (int k = 0; k < 4; ++k) {
                const unsigned fe = fw4[k] << 16;          // even px as f32 bits
                const unsigned fo = fw4[k] & 0xFFFF0000u;  // odd px as f32 bits
                const unsigned mw = mw4[k];
                #pragma unroll
                for (int j = 0; j < 16; ++j) {
                    unsigned m0 = (unsigned)(((int)(mw << (31 - j))) >> 31); // bfe bit j
                    unsigned m1 = (unsigned)(((int)(mw << (15 - j))) >> 31); // bit j+16
                    float s0 = __uint_as_float((fe & m0) | (NEGI & ~m0));    // bfi
                    float s1 = __uint_as_float((fo & m1) | (NEGI & ~m1));
                    vmax[j] = fmaxf(fmaxf(vmax[j], s0), s1);                 // max3
                }
            }
        }
    } else {
        const float* fp = (const float*)featv + (((size_t)(b * CCH + c)) << 12);
        #pragma unroll
        for (int i = 0; i < 8; ++i) {
            const float* cp = fp + (i * 64 + l) * 8;
            uint4 q0 = *(const uint4*)(cp);
            uint4 q1 = *(const uint4*)(cp + 4);
            const unsigned pe4[4] = {q0.x, q0.z, q1.x, q1.z};  // even px
            const unsigned po4[4] = {q0.y, q0.w, q1.y, q1.w};  // odd px
            const unsigned mw4[4] = {pm[i].x, pm[i].y, pm[i].z, pm[i].w};
            #pragma unroll
            for (int k = 0; k < 4; ++k) {
                const unsigned fe = pe4[k];
                const unsigned fo = po4[k];
                const unsigned mw = mw4[k];
                #pragma unroll
                for (int j = 0; j < 16; ++j) {
                    unsigned m0 = (unsigned)(((int)(mw << (31 - j))) >> 31);
                    unsigned m1 = (unsigned)(((int)(mw << (15 - j))) >> 31);
                    float s0 = __uint_as_float((fe & m0) | (NEGI & ~m0));
                    float s1 = __uint_as_float((fo & m1) | (NEGI & ~m1));
                    vmax[j] = fmaxf(fmaxf(vmax[j], s0), s1);
                }
            }
        }
    }

    // 64-lane butterfly max: after this every lane holds all 16 cell maxes.
    #pragma unroll
    for (int d = 1; d < 64; d <<= 1) {
        #pragma unroll
        for (int j = 0; j < 16; ++j)
            vmax[j] = fmaxf(vmax[j], __shfl_xor(vmax[j], d, 64));
    }

    // lane j takes cell j via compile-time select chain (no runtime reg index)
    float v = vmax[0];
    #pragma unroll
    for (int j = 1; j < 16; ++j) v = (l == j) ? vmax[j] : v;

    if (l < 16 && l < cnt) {
        const size_t oi = (size_t)(start + l) * CCH + c;
        if (fbf16) ((__hip_bfloat16*)outv)[oi] = __float2bfloat16(v);
        else       ((float*)outv)[oi]          = v;
    }
}

extern "C" void kernel_launch(void* const* d_in, const int* in_sizes, int n_in,
                              void* d_out, int out_size, void* d_ws, size_t ws_size,
                              hipStream_t stream) {
    const void* feat  = d_in[0];
    const void* masks = d_in[1];
    const int* counts = (const int*)d_in[2];
    unsigned short* packed = (unsigned short*)d_ws;   // 8*4096*2 = 64 KiB

    pack_masks<<<(BIMG * HW) / 64, 64, 0, stream>>>(masks, counts, packed);

    roipool_main<<<(BIMG * CCH) / 4, 256, 0, stream>>>(feat, packed, counts, d_out);
}

// Round 2
// 88.201 us; speedup vs baseline: 1.3373x; 1.3373x over previous
//
#include <hip/hip_runtime.h>
#include <hip/hip_bf16.h>

// RoIPool max over boolean cell masks (harness bf16-ifies floats AND bools).
// B=8, C=256, H=W=64 (HW=4096), N=128 cells (16/image).
// R7 structure (post-mortem R6: one-wave-per-(b,c) spilled 560 B/thread ->
// 73 MB scratch writes, 48.5us latency-bound. Fix: back to R5's register
// geometry (16 px/thread, ~60 VGPR, no spill), with R6's cheap reduction):
//   kernel 1: pack 16 cell masks/image -> uint16 per pixel (64 KB in d_ws).
//             Fully-unrolled cnt==16 fast path (16 mask loads in flight).
//   kernel 2: one 256-thr block per (b,c) = 2048 blocks. 16 px/thread,
//             bit-domain select (bfe+bfi+max3), 64-lane shfl_xor butterfly
//             per wave, then ONE barrier + 320 B LDS to combine 4 waves.
//             Wave-level dtype detect (ballot, no barrier, no LDS).

#define HW    4096
#define BIMG  8
#define CCH   256
#define NCELL 128

__device__ __forceinline__ void cell_range(const int* counts, int b, int& start, int& cnt) {
    start = 0;
    for (int i = 0; i < b; ++i) start += counts[i];
    if (start > NCELL) start = NCELL;
    cnt = counts[b];
    // jnp.repeat(..., total_repeat_length=N) pads with the last value:
    if (b == BIMG - 1 && start + cnt < NCELL) cnt = NCELL - start;
    if (cnt > 16) cnt = 16;
    if (start + cnt > NCELL) cnt = NCELL - start;
    if (cnt < 0) cnt = 0;
}

// ---- kernel 1: bit-pack masks. grid 128 x 256 threads = 32768 = BIMG*HW ----
__global__ __launch_bounds__(256)
void pack_masks(const void* __restrict__ maskv,
                const int* __restrict__ counts,
                unsigned short* __restrict__ packed) {
    const int tid = threadIdx.x;
    const int l   = tid & 63;
    const int idx = blockIdx.x * 256 + tid;      // b*HW + p
    const int b = idx >> 12;
    const int p = idx & (HW - 1);

    // mask element size from byte-lane OR of first 1 KiB (proven R3..R6),
    // wave-level: butterfly OR, no LDS, no barrier.
    const unsigned* mw0 = (const unsigned*)maskv;
    unsigned ow = mw0[l * 4] | mw0[l * 4 + 1] | mw0[l * 4 + 2] | mw0[l * 4 + 3];
    #pragma unroll
    for (int d = 1; d < 64; d <<= 1) ow |= __shfl_xor(ow, d, 64);
    const unsigned or0 = ow & 0xFFu, or1 = (ow >> 8) & 0xFFu;
    int msize;
    if (or1 == 0)                        msize = 4;  // int32/f32 masks
    else if (or0 == 0x80 || or0 == 0x00) msize = 2;  // bf16 (3F80) / f16 (3C00)
    else                                 msize = 1;  // bool/uint8

    int start, cnt;
    cell_range(counts, b, start, cnt);

    unsigned w = 0;
    if (msize == 2) {
        const unsigned short* mh = (const unsigned short*)maskv + (size_t)start * HW + p;
        if (cnt == 16) {
            #pragma unroll
            for (int j = 0; j < 16; ++j)
                w |= (mh[(size_t)j * HW] ? 1u : 0u) << j;   // 16 loads in flight
        } else {
            for (int j = 0; j < cnt; ++j)
                w |= (mh[(size_t)j * HW] ? 1u : 0u) << j;
        }
    } else if (msize == 4) {
        const unsigned* mw = (const unsigned*)maskv + (size_t)start * HW + p;
        if (cnt == 16) {
            #pragma unroll
            for (int j = 0; j < 16; ++j)
                w |= (mw[(size_t)j * HW] ? 1u : 0u) << j;
        } else {
            for (int j = 0; j < cnt; ++j)
                w |= (mw[(size_t)j * HW] ? 1u : 0u) << j;
        }
    } else {
        const unsigned char* mb = (const unsigned char*)maskv + (size_t)start * HW + p;
        if (cnt == 16) {
            #pragma unroll
            for (int j = 0; j < 16; ++j)
                w |= (mb[(size_t)j * HW] ? 1u : 0u) << j;
        } else {
            for (int j = 0; j < cnt; ++j)
                w |= (mb[(size_t)j * HW] ? 1u : 0u) << j;
        }
    }
    packed[idx] = (unsigned short)w;
}

// ---- kernel 2: one 256-thr block per (b, c). grid (256, 8) ----
__global__ __launch_bounds__(256, 4)
void roipool_main(const void* __restrict__ featv,
                  const unsigned short* __restrict__ packed,
                  const int* __restrict__ counts,
                  void* __restrict__ outv) {
    const int c   = blockIdx.x;
    const int b   = blockIdx.y;
    const int tid = threadIdx.x;
    const int l   = tid & 63;      // lane
    const int wv  = tid >> 6;      // wave 0..3
    const float NEG = -__builtin_inff();
    const unsigned NEGI = 0xFF800000u;   // f32 -inf bits

    // feature dtype: bf16 iff byte1 of each dword looks like a bf16 exponent
    // byte (proven R5/R6) — per-wave ballot, no LDS, no barrier.
    const unsigned* fw_ = (const unsigned*)featv;
    const unsigned w0 = fw_[l];
    const unsigned eb = (w0 >> 8) & 0x7F;
    const unsigned long long bm = __ballot(eb >= 0x3B && eb <= 0x41);
    const int fbf16 = (__popcll(bm) >= 48);

    int start, cnt;
    cell_range(counts, b, start, cnt);

    const int p0 = tid * 16;   // this thread's 16 pixels

    // packed masks: 16 uint16 = 32 B; dword k holds masks of px (2k, 2k+1)
    uint4 pa = *(const uint4*)(packed + ((size_t)b << 12) + p0);
    uint4 pb = *(const uint4*)(packed + ((size_t)b << 12) + p0 + 8);
    const unsigned pmw[8] = {pa.x, pa.y, pa.z, pa.w, pb.x, pb.y, pb.z, pb.w};

    // features as f32 bit patterns: pair k = pixels (2k, 2k+1)
    unsigned pe[8], po[8];
    if (fbf16) {
        const unsigned short* fp = (const unsigned short*)featv
                                 + (((size_t)(b * CCH + c)) << 12) + p0;
        uint4 f0 = *(const uint4*)(fp);
        uint4 f1 = *(const uint4*)(fp + 8);
        const unsigned w8[8] = {f0.x, f0.y, f0.z, f0.w, f1.x, f1.y, f1.z, f1.w};
        #pragma unroll
        for (int k = 0; k < 8; ++k) {
            pe[k] = w8[k] << 16;          // even px as f32 bits
            po[k] = w8[k] & 0xFFFF0000u;  // odd px as f32 bits
        }
    } else {
        const float* fp = (const float*)featv + (((size_t)(b * CCH + c)) << 12) + p0;
        #pragma unroll
        for (int q = 0; q < 4; ++q) {
            uint4 a = *(const uint4*)(fp + q * 4);
            pe[q * 2]     = a.x; po[q * 2]     = a.y;
            pe[q * 2 + 1] = a.z; po[q * 2 + 1] = a.w;
        }
    }

    float vmax[16];
    #pragma unroll
    for (int j = 0; j < 16; ++j) vmax[j] = NEG;

    #pragma unroll
    for (int k = 0; k < 8; ++k) {
        const unsigned fe = pe[k], fo = po[k];
        const unsigned mw = pmw[k];   // bits 0..15: px 2k; bits 16..31: px 2k+1
        #pragma unroll
        for (int j = 0; j < 16; ++j) {
            unsigned m0 = (unsigned)(((int)(mw << (31 - j))) >> 31);  // bfe_i32 bit j
            unsigned m1 = (unsigned)(((int)(mw << (15 - j))) >> 31);  // bit j+16
            float s0 = __uint_as_float((fe & m0) | (NEGI & ~m0));     // bfi_b32
            float s1 = __uint_as_float((fo & m1) | (NEGI & ~m1));
            vmax[j] = fmaxf(fmaxf(vmax[j], s0), s1);                  // max3_f32
        }
    }

    // 64-lane butterfly max: every lane of each wave holds all 16 cell maxes
    // for that wave's 1024 pixels. 96 shfl + 96 max per wave.
    #pragma unroll
    for (int d = 1; d < 64; d <<= 1) {
        #pragma unroll
        for (int j = 0; j < 16; ++j)
            vmax[j] = fmaxf(vmax[j], __shfl_xor(vmax[j], d, 64));
    }

    // lane j takes cell j via compile-time select chain (no runtime reg index)
    float v = vmax[0];
    #pragma unroll
    for (int j = 1; j < 16; ++j) v = (l == j) ? vmax[j] : v;

    // cross-wave combine: 4 waves x 16 cells, ONE barrier, 320 B LDS.
    __shared__ float red[4][16];
    if (l < 16) red[wv][l] = v;
    __syncthreads();
    if (tid < 16) {
        float m = fmaxf(fmaxf(red[0][tid], red[1][tid]),
                        fmaxf(red[2][tid], red[3][tid]));
        if (tid < cnt) {
            const size_t oi = (size_t)(start + tid) * CCH + c;
            if (fbf16) ((__hip_bfloat16*)outv)[oi] = __float2bfloat16(m);
            else       ((float*)outv)[oi]          = m;
        }
    }
}

extern "C" void kernel_launch(void* const* d_in, const int* in_sizes, int n_in,
                              void* d_out, int out_size, void* d_ws, size_t ws_size,
                              hipStream_t stream) {
    const void* feat  = d_in[0];
    const void* masks = d_in[1];
    const int* counts = (const int*)d_in[2];
    unsigned short* packed = (unsigned short*)d_ws;   // 8*4096*2 = 64 KiB

    pack_masks<<<(BIMG * HW) / 256, 256, 0, stream>>>(masks, counts, packed);

    dim3 grid(CCH, BIMG);   // 2048 blocks, one per (b, c)
    roipool_main<<<grid, 256, 0, stream>>>(feat, packed, counts, d_out);
}